// Round 2
// baseline (2149.303 us; speedup 1.0000x reference)
//
#include <hip/hip_runtime.h>
#include <math.h>

#define N_PTS 131072
#define KC 64
#define DF 512
#define LF 10

// ---- workspace layout (floats) ----
// Wmat : [DF][KC*12]  d-major; per k the 12 cols are [iD | iD*MU | B0..B9]
// iL   : [KC][LF*LF]
// tmu  : [KC][LF]
// C    : [KC]
#define WMAT_SZ (DF * KC * 12)
#define IL_OFF  (WMAT_SZ)
#define IL_SZ   (KC * LF * LF)
#define TMU_OFF (IL_OFF + IL_SZ)
#define TMU_SZ  (KC * LF)
#define C_OFF   (TMU_OFF + TMU_SZ)

// ======================= prep: per-component constants =======================
// LDS kept < 8 KB (no sA tile; phase b reads A via L1/L2 — 20 KB/component).
__global__ __launch_bounds__(256) void mfa_prep_kernel(
    const float* __restrict__ MU, const float* __restrict__ A,
    const float* __restrict__ D, const float* __restrict__ PI,
    float* __restrict__ ws)
{
    __shared__ float siD[DF];
    __shared__ float sMU[DF];
    __shared__ float red[256];
    __shared__ float red2[256];
    __shared__ float sL[LF * LF];
    __shared__ float stmu[LF];

    const int k = blockIdx.x;
    const int t = threadIdx.x;
    float* Wmat = ws;

    // phase a: stage iD/MU, write Wmat, partial-reduce mu^T iD mu and sum(log D)
    float c0p = 0.f, slp = 0.f;
    for (int d = t; d < DF; d += 256) {
        float Dv = D[k * DF + d];
        float mu = MU[k * DF + d];
        float id = 1.0f / (Dv * Dv);
        siD[d] = id;
        sMU[d] = mu;
        c0p += id * mu * mu;
        slp += logf(Dv);
        float* wrow = &Wmat[(size_t)d * (KC * 12) + k * 12];
        wrow[0] = id;
        wrow[1] = id * mu;
        #pragma unroll
        for (int l = 0; l < LF; l++) {
            float a = A[((size_t)k * DF + d) * LF + l];
            wrow[2 + l] = id * a;
        }
    }
    red[t] = c0p;
    red2[t] = slp;
    __syncthreads();
    for (int s = 128; s > 0; s >>= 1) {
        if (t < s) { red[t] += red[t + s]; red2[t] += red2[t + s]; }
        __syncthreads();
    }

    // phase b: L = I + A^T (iD*A)  (100 entries), tmu = B^T MU  (A from global/L1)
    const float* Ak = &A[(size_t)k * DF * LF];
    if (t < 100) {
        int l = t / 10, m = t % 10;
        float s = (l == m) ? 1.0f : 0.0f;
        for (int d = 0; d < DF; d++) s += Ak[d * LF + l] * siD[d] * Ak[d * LF + m];
        sL[l * 10 + m] = s;
    } else if (t < 110) {
        int l = t - 100;
        float s = 0.f;
        for (int d = 0; d < DF; d++) s += Ak[d * LF + l] * siD[d] * sMU[d];
        stmu[l] = s;
    }
    __syncthreads();

    // phase c: thread 0 inverts 10x10 SPD via Gauss-Jordan, logdet from pivots
    if (t == 0) {
        float M[LF][LF], Iv[LF][LF];
        for (int i = 0; i < LF; i++)
            for (int j = 0; j < LF; j++) {
                M[i][j] = sL[i * 10 + j];
                Iv[i][j] = (i == j) ? 1.f : 0.f;
            }
        float logdet = 0.f;
        for (int i = 0; i < LF; i++) {
            float p = M[i][i];
            logdet += logf(p);
            float ip = 1.0f / p;
            for (int j = 0; j < LF; j++) { M[i][j] *= ip; Iv[i][j] *= ip; }
            for (int r = 0; r < LF; r++) if (r != i) {
                float f = M[r][i];
                for (int j = 0; j < LF; j++) { M[r][j] -= f * M[i][j]; Iv[r][j] -= f * Iv[i][j]; }
            }
        }
        float c0 = red[0];
        float sumlogiD = -2.0f * red2[0];       // sum(log iD) = -2 sum(log D)
        float logdetSigma = logdet - sumlogiD;
        const float LOG2PI = 1.8378770664093453f;
        float C = PI[k] - 0.5f * (DF * LOG2PI + logdetSigma + c0);
        float* iL = &ws[IL_OFF + k * LF * LF];
        for (int i = 0; i < LF * LF; i++) iL[i] = Iv[i / LF][i % LF];
        float* tm = &ws[TMU_OFF + k * LF];
        for (int l = 0; l < LF; l++) tm[l] = stmu[l];
        ws[C_OFF + k] = C;
    }
}

// ======================= main: fused GEMM + epilogue =========================
// block tile: BN=128 rows x (KG=16 k's * 12 = 192 cols), BK=16, 256 threads
// micro-tile: 8 rows x 12 cols (one k) per thread
#define BN 128
#define KG 16
#define BKD 16

__global__ __launch_bounds__(256) void mfa_main_kernel(
    const float* __restrict__ x, const float* __restrict__ ws,
    float* __restrict__ out)
{
    __shared__ float sx[BKD][BN];          // 8 KB, [d][row]
    __shared__ float sw[BKD][KG * 12];     // 12 KB, [d][col]
    __shared__ float siL[KG][LF * LF];     // 6.4 KB
    __shared__ float stmu[KG][LF];
    __shared__ float sC[KG];

    const int t = threadIdx.x;
    const int kg0 = blockIdx.x * KG;       // col-group in fast dim -> x reuse in L2
    const int n0 = blockIdx.y * BN;

    // stage epilogue constants
    for (int i = t; i < KG * LF * LF; i += 256) {
        int kk = i / (LF * LF), r = i % (LF * LF);
        siL[kk][r] = ws[IL_OFF + (size_t)(kg0 + kk) * LF * LF + r];
    }
    for (int i = t; i < KG * LF; i += 256) {
        int kk = i / LF, r = i % LF;
        stmu[kk][r] = ws[TMU_OFF + (size_t)(kg0 + kk) * LF + r];
    }
    if (t < KG) sC[t] = ws[C_OFF + kg0 + t];

    const int cg = t & 15;                 // k within group
    const int rg = t >> 4;                 // 0..15
    const int r0 = rg * 8;
    const int c0 = cg * 12;

    float accg1[8] = {0.f, 0.f, 0.f, 0.f, 0.f, 0.f, 0.f, 0.f};
    float accg2[8] = {0.f, 0.f, 0.f, 0.f, 0.f, 0.f, 0.f, 0.f};
    float accT[8][10];
    #pragma unroll
    for (int r = 0; r < 8; r++)
        #pragma unroll
        for (int l = 0; l < LF; l++) accT[r][l] = 0.f;

    const float* Wm = ws;

    for (int d0 = 0; d0 < DF; d0 += BKD) {
        __syncthreads();
        // stage x tile (transposed to [d][row]); 2 float4 per thread
        #pragma unroll
        for (int i = 0; i < 2; i++) {
            int f = t + i * 256;
            int row = f >> 2, fo = f & 3;
            float4 v = *(const float4*)&x[(size_t)(n0 + row) * DF + d0 + fo * 4];
            sx[fo * 4 + 0][row] = v.x;
            sx[fo * 4 + 1][row] = v.y;
            sx[fo * 4 + 2][row] = v.z;
            sx[fo * 4 + 3][row] = v.w;
        }
        // stage W tile; 3 float4 per thread (row-contiguous in Wmat)
        #pragma unroll
        for (int i = 0; i < 3; i++) {
            int f = t + i * 256;
            int d = f / 48, ci = (f % 48) * 4;
            float4 v = *(const float4*)&Wm[(size_t)(d0 + d) * (KC * 12) + kg0 * 12 + ci];
            *(float4*)&sw[d][ci] = v;
        }
        __syncthreads();

        #pragma unroll
        for (int d = 0; d < BKD; d++) {
            float4 xa = *(float4*)&sx[d][r0];
            float4 xb = *(float4*)&sx[d][r0 + 4];
            float4 w0 = *(float4*)&sw[d][c0];
            float4 w1 = *(float4*)&sw[d][c0 + 4];
            float4 w2 = *(float4*)&sw[d][c0 + 8];
            float xs[8] = {xa.x, xa.y, xa.z, xa.w, xb.x, xb.y, xb.z, xb.w};
            #pragma unroll
            for (int r = 0; r < 8; r++) {
                float xv = xs[r];
                float x2 = xv * xv;
                accg1[r] += x2 * w0.x;
                accg2[r] += xv * w0.y;
                accT[r][0] += xv * w0.z;
                accT[r][1] += xv * w0.w;
                accT[r][2] += xv * w1.x;
                accT[r][3] += xv * w1.y;
                accT[r][4] += xv * w1.z;
                accT[r][5] += xv * w1.w;
                accT[r][6] += xv * w2.x;
                accT[r][7] += xv * w2.y;
                accT[r][8] += xv * w2.z;
                accT[r][9] += xv * w2.w;
            }
        }
    }

    // epilogue: q2 = (T - tmu)^T iL (T - tmu);  out = C - 0.5*g1 + g2 + 0.5*q2
    const int kidx = kg0 + cg;
    const float Cv = sC[cg];
    #pragma unroll
    for (int r = 0; r < 8; r++) {
        float tl[10];
        #pragma unroll
        for (int l = 0; l < LF; l++) tl[l] = accT[r][l] - stmu[cg][l];
        float q2 = 0.f;
        #pragma unroll
        for (int l = 0; l < LF; l++) {
            float s = 0.f;
            #pragma unroll
            for (int m = 0; m < LF; m++) s += siL[cg][l * LF + m] * tl[m];
            q2 += s * tl[l];
        }
        float val = Cv - 0.5f * accg1[r] + accg2[r] + 0.5f * q2;
        out[(size_t)(n0 + r0 + r) * KC + kidx] = val;
    }
}

// ================================ launch =====================================
extern "C" void kernel_launch(void* const* d_in, const int* in_sizes, int n_in,
                              void* d_out, int out_size, void* d_ws, size_t ws_size,
                              hipStream_t stream) {
    const float* x  = (const float*)d_in[0];
    const float* MU = (const float*)d_in[1];
    const float* A  = (const float*)d_in[2];
    const float* D  = (const float*)d_in[3];
    const float* PI = (const float*)d_in[4];
    float* out = (float*)d_out;
    float* ws  = (float*)d_ws;

    mfa_prep_kernel<<<KC, 256, 0, stream>>>(MU, A, D, PI, ws);
    mfa_main_kernel<<<dim3(KC / KG, N_PTS / BN), 256, 0, stream>>>(x, ws, out);
}

// Round 3
// 789.485 us; speedup vs baseline: 2.7224x; 2.7224x over previous
//
#include <hip/hip_runtime.h>
#include <math.h>
#include <stdint.h>

#define N_PTS 131072
#define KC 64
#define DF 512
#define LF 10

typedef __bf16 bf16x8 __attribute__((ext_vector_type(8)));
typedef float f32x4 __attribute__((ext_vector_type(4)));

union U128 { bf16x8 v; uint4 q; uint32_t w[4]; __bf16 e[8]; };

// ---- workspace byte offsets ----
#define W_OFF   0u            // Wmat2: [64k][16col][512d] bf16 = 1 MB (cols: iDmu | B''0..9 | iD-col is NOT here (zero) )
#define ID_OFF  1048576u      // IDmat: [64k][512d] bf16 = 64 KB
#define CCG_OFF 1114112u      // colconst: [64k][16col] float4 = 16 KB  (w2, w1, shift, 0)
#define CV_OFF  1130496u      // C: [64] float

__device__ __forceinline__ uint16_t f2bf(float f) {
    uint32_t u = __float_as_uint(f);
    uint32_t r = (u + 0x7FFFu + ((u >> 16) & 1u)) >> 16;
    return (uint16_t)r;
}

// ======================= prep: per-component constants =======================
__global__ __launch_bounds__(256) void mfa_prep(
    const float* __restrict__ MU, const float* __restrict__ A,
    const float* __restrict__ D, const float* __restrict__ PI,
    char* __restrict__ ws)
{
    __shared__ float siD[DF], sMU[DF], red[256], red2[256], sL[100], stm[10], sU[100];
    const int k = blockIdx.x, t = threadIdx.x;
    uint16_t* Wm  = (uint16_t*)(ws + W_OFF);
    uint16_t* IDm = (uint16_t*)(ws + ID_OFF);
    float4*   CCg = (float4*)(ws + CCG_OFF);
    float*    Cg  = (float*)(ws + CV_OFF);

    float c0p = 0.f, slp = 0.f;
    for (int d = t; d < DF; d += 256) {
        float Dv = D[k*DF + d], mu = MU[k*DF + d];
        float id = 1.f/(Dv*Dv);
        siD[d] = id; sMU[d] = mu;
        c0p += id*mu*mu; slp += logf(Dv);
    }
    red[t] = c0p; red2[t] = slp;
    __syncthreads();
    for (int s = 128; s > 0; s >>= 1) { if (t < s) { red[t]+=red[t+s]; red2[t]+=red2[t+s]; } __syncthreads(); }

    const float* Ak = A + (size_t)k*DF*LF;
    if (t < 100) {
        int l = t/10, m = t%10;
        float s = (l==m)?1.f:0.f;
        for (int d = 0; d < DF; d++) s += Ak[d*LF+l]*siD[d]*Ak[d*LF+m];
        sL[t] = s;
    } else if (t < 110) {
        int l = t-100; float s = 0.f;
        for (int d = 0; d < DF; d++) s += Ak[d*LF+l]*siD[d]*sMU[d];
        stm[l] = s;
    }
    __syncthreads();

    if (t == 0) {
        // Cholesky L = G G^T (lower), logdetL = 2*sum log Gii
        float G[LF][LF];
        for (int i = 0; i < LF; i++) for (int j = 0; j < LF; j++) G[i][j] = 0.f;
        float logdet = 0.f;
        for (int j = 0; j < LF; j++) {
            float s = sL[j*10+j];
            for (int m = 0; m < j; m++) s -= G[j][m]*G[j][m];
            float gjj = sqrtf(s); G[j][j] = gjj; logdet += 2.f*logf(gjj);
            for (int i = j+1; i < LF; i++) {
                float v = sL[i*10+j];
                for (int m = 0; m < j; m++) v -= G[i][m]*G[j][m];
                G[i][j] = v / gjj;
            }
        }
        // U = G^-1 (lower);  iL = U^T U;  q2 = ||U t||^2
        float Ut[LF][LF];
        for (int i = 0; i < LF; i++) for (int j = 0; j < LF; j++) Ut[i][j] = 0.f;
        for (int j = 0; j < LF; j++) {
            Ut[j][j] = 1.f/G[j][j];
            for (int i = j+1; i < LF; i++) {
                float s = 0.f;
                for (int m = j; m < i; m++) s += G[i][m]*Ut[m][j];
                Ut[i][j] = -s/G[i][i];
            }
        }
        for (int i = 0; i < 100; i++) sU[i] = Ut[i/10][i%10];
        float tmu2[LF];
        for (int l = 0; l < LF; l++) { float s = 0.f; for (int m = 0; m <= l; m++) s += Ut[l][m]*stm[m]; tmu2[l] = s; }
        float sumlogiD = -2.f*red2[0];
        const float LOG2PI = 1.8378770664093453f;
        float C = PI[k] - 0.5f*((float)DF*LOG2PI + (logdet - sumlogiD) + red[0]);
        Cg[k] = C;
        for (int col = 0; col < 16; col++) {
            float4 cc;
            if (col == 0)       cc = make_float4(0.f, 1.f, 0.f, 0.f);     // g2: +a
            else if (col <= 10) cc = make_float4(0.5f, 0.f, tmu2[col-1], 0.f); // +0.5(a-s)^2
            else if (col == 11) cc = make_float4(0.f, -0.5f, 0.f, 0.f);   // g1: -0.5a
            else                cc = make_float4(0.f, 0.f, 0.f, 0.f);
            CCg[k*16 + col] = cc;
        }
    }
    __syncthreads();

    // write Wmat2 (bf16): col0 = iD*mu, col1..10 = iD * (A U^T)[d][l], col11..15 = 0; IDmat = iD
    for (int d = t; d < DF; d += 256) {
        float id = siD[d], mu = sMU[d];
        float a[LF];
        #pragma unroll
        for (int m = 0; m < LF; m++) a[m] = Ak[d*LF + m];
        uint16_t* wr = Wm + (size_t)k*16*DF + d;
        wr[0] = f2bf(id*mu);
        for (int l = 0; l < LF; l++) {
            float s = 0.f;
            for (int m = 0; m <= l; m++) s += a[m]*sU[l*10+m];
            wr[(size_t)(1+l)*DF] = f2bf(id*s);
        }
        for (int col = 11; col < 16; col++) wr[(size_t)col*DF] = 0;
        IDm[(size_t)k*DF + d] = f2bf(id);
    }
}

// ======================= main: 2-pass bf16 MFMA GEMM =========================
// block: 512 thr / 8 waves = 2 rowgroups x 4 k-quads; tile 128 rows x 16 k
// wave: 64 rows x 4 k (4x4 fragment tiles), DK=64 per iter, double-buffered
#define LDS_SX 0          // x bf16 [2][128 rows][64 d] swizzled, 2x16KB
#define LDS_SW 32768      // w bf16 [2][16 k][16 col][64 d] swizzled, 2x32KB
#define LDS_SI 98304      // iD bf16 [2][16 k][64 d] linear, 2x2KB
#define LDS_CC 102400     // colconst [16k][16col] float4, 4KB
#define LDS_SC 106496     // C [16] f32
#define LDS_TOT 106560

__global__ __launch_bounds__(512, 2) void mfa_main(
    const float* __restrict__ x, const char* __restrict__ ws,
    float* __restrict__ out)
{
    __shared__ __align__(16) char LDS[LDS_TOT];
    const int t = threadIdx.x;

    // XCD-bijective remap: each XCD gets a contiguous row-band; all 4 kgroups
    // of a row-band co-resident on one XCD -> x L2-reuse across kgroups.
    const int lin = blockIdx.y*4 + blockIdx.x;          // 0..4095, x fastest
    const int logical = (lin & 7)*512 + (lin >> 3);     // bijective (4096 = 8*512)
    const int kg0 = (logical & 3)*16;
    const int n0  = (logical >> 2)*128;

    const uint16_t* Wm  = (const uint16_t*)(ws + W_OFF);
    const uint16_t* IDm = (const uint16_t*)(ws + ID_OFF);

    if (t < 256) {  // colconst [kk][col] -> LDS, t = kk*16+col
        const float4* CCg = (const float4*)(ws + CCG_OFF);
        *(float4*)(LDS + LDS_CC + t*16) = CCg[kg0*16 + t];
    }
    if (t < 16) *(float*)(LDS + LDS_SC + t*4) = ((const float*)(ws + CV_OFF))[kg0 + t];

    const int lane = t & 63, w = t >> 6;
    const int rg = w >> 2, kq = w & 3;
    const int lm = lane & 15, lg = lane >> 4;
    const bool is11 = (lm == 11);

    // fragment LDS byte offsets (ks=0); ks=1 flips slot by 4 -> XOR 64
    int aoff[4], boff[4], ioff[4];
    #pragma unroll
    for (int rt = 0; rt < 4; rt++) {
        int row = rg*64 + rt*16 + lm;
        aoff[rt] = row*128 + (((lg + row)&7)<<4);
    }
    #pragma unroll
    for (int kt = 0; kt < 4; kt++) {
        int kk = kq*4 + kt;
        boff[kt] = kk*2048 + lm*128 + (((lg + lm)&7)<<4);
        ioff[kt] = kk*128 + (lg<<4);
    }

    // staging assignments
    const int srow = t >> 2, sq = t & 3;                 // x: row, 16-float chunk-pair
    const float* xsrc = x + (size_t)(n0 + srow)*DF + sq*16;
    const int sxdst = srow*128;
    const int slot0 = ((2*sq + 0) + srow) & 7;
    const int slot1 = ((2*sq + 1) + srow) & 7;
    const int wk = t >> 5, wcol = (t >> 1) & 15, wh = t & 1;
    const uint16_t* wsrc = Wm + ((size_t)(kg0 + wk)*16 + wcol)*DF + wh*32;
    const int swb = wk*2048 + wcol*128;
    const uint16_t* isrc = IDm + (size_t)(kg0 + (t>>3))*DF + (t&7)*8;
    const int sib = (t>>3)*128 + (t&7)*16;

    f32x4 acc[4][4];
    #pragma unroll
    for (int i = 0; i < 4; i++)
        #pragma unroll
        for (int j = 0; j < 4; j++) acc[i][j] = (f32x4){0.f, 0.f, 0.f, 0.f};

    float4 gx0, gx1, gx2, gx3; uint4 gw0, gw1, gw2, gw3; uint4 gi;

#define LOAD(IT) do { \
    const float* xb = xsrc + (IT)*64; \
    gx0 = *(const float4*)(xb);     gx1 = *(const float4*)(xb + 4); \
    gx2 = *(const float4*)(xb + 8); gx3 = *(const float4*)(xb + 12); \
    const uint16_t* wb = wsrc + (IT)*64; \
    gw0 = *(const uint4*)(wb);      gw1 = *(const uint4*)(wb + 8); \
    gw2 = *(const uint4*)(wb + 16); gw3 = *(const uint4*)(wb + 24); \
    if (t < 128) gi = *(const uint4*)(isrc + (IT)*64); \
} while (0)

#define WRITE(BUF) do { \
    char* px = LDS + LDS_SX + (BUF)*16384; \
    U128 u0, u1; \
    u0.e[0]=(__bf16)gx0.x; u0.e[1]=(__bf16)gx0.y; u0.e[2]=(__bf16)gx0.z; u0.e[3]=(__bf16)gx0.w; \
    u0.e[4]=(__bf16)gx1.x; u0.e[5]=(__bf16)gx1.y; u0.e[6]=(__bf16)gx1.z; u0.e[7]=(__bf16)gx1.w; \
    u1.e[0]=(__bf16)gx2.x; u1.e[1]=(__bf16)gx2.y; u1.e[2]=(__bf16)gx2.z; u1.e[3]=(__bf16)gx2.w; \
    u1.e[4]=(__bf16)gx3.x; u1.e[5]=(__bf16)gx3.y; u1.e[6]=(__bf16)gx3.z; u1.e[7]=(__bf16)gx3.w; \
    *(uint4*)(px + sxdst + slot0*16) = u0.q; \
    *(uint4*)(px + sxdst + slot1*16) = u1.q; \
    char* pw = LDS + LDS_SW + (BUF)*32768; \
    *(uint4*)(pw + swb + ((((wh*4+0)+wcol)&7)<<4)) = gw0; \
    *(uint4*)(pw + swb + ((((wh*4+1)+wcol)&7)<<4)) = gw1; \
    *(uint4*)(pw + swb + ((((wh*4+2)+wcol)&7)<<4)) = gw2; \
    *(uint4*)(pw + swb + ((((wh*4+3)+wcol)&7)<<4)) = gw3; \
    if (t < 128) *(uint4*)(LDS + LDS_SI + (BUF)*2048 + sib) = gi; \
} while (0)

    LOAD(0);
    WRITE(0);
    __syncthreads();

    for (int it = 0; it < 8; ++it) {
        const int cur = it & 1;
        if (it < 7) LOAD(it + 1);

        {
            const char* px = LDS + LDS_SX + cur*16384;
            const char* pw = LDS + LDS_SW + cur*32768;
            const char* pi = LDS + LDS_SI + cur*2048;
            #pragma unroll
            for (int ks = 0; ks < 2; ++ks) {
                const int xr = ks ? 64 : 0;
                bf16x8 av[4], bv[4];
                #pragma unroll
                for (int rt = 0; rt < 4; rt++) av[rt] = *(const bf16x8*)(px + (aoff[rt] ^ xr));
                #pragma unroll
                for (int kt = 0; kt < 4; kt++) bv[kt] = *(const bf16x8*)(pw + (boff[kt] ^ xr));
                #pragma unroll
                for (int rt = 0; rt < 4; rt++)
                    #pragma unroll
                    for (int kt = 0; kt < 4; kt++)
                        acc[rt][kt] = __builtin_amdgcn_mfma_f32_16x16x32_bf16(av[rt], bv[kt], acc[rt][kt], 0, 0, 0);
                // pass 2: x^2 against iD (col 11 only)
                bf16x8 a2[4], b2[4];
                #pragma unroll
                for (int rt = 0; rt < 4; rt++) {
                    #pragma unroll
                    for (int j = 0; j < 8; j++) {
                        float f = (float)av[rt][j];
                        a2[rt][j] = (__bf16)(f*f);
                    }
                }
                #pragma unroll
                for (int kt = 0; kt < 4; kt++) {
                    U128 s, o;
                    s.v = *(const bf16x8*)(pi + ioff[kt] + xr);
                    #pragma unroll
                    for (int q = 0; q < 4; q++) o.w[q] = is11 ? s.w[q] : 0u;
                    b2[kt] = o.v;
                }
                #pragma unroll
                for (int rt = 0; rt < 4; rt++)
                    #pragma unroll
                    for (int kt = 0; kt < 4; kt++)
                        acc[rt][kt] = __builtin_amdgcn_mfma_f32_16x16x32_bf16(a2[rt], b2[kt], acc[rt][kt], 0, 0, 0);
            }
        }

        if (it < 7) WRITE(cur ^ 1);
        __syncthreads();
    }

    // epilogue: per-col f(a) = w1*a + w2*(a-s)^2, reduce across 16 cols, + C_k
    #pragma unroll
    for (int kt = 0; kt < 4; kt++) {
        const int kk = kq*4 + kt;
        const float4 cc = *(const float4*)(LDS + LDS_CC + (kk*16 + lm)*16);
        const float Ck = *(const float*)(LDS + LDS_SC + kk*4);
        #pragma unroll
        for (int rt = 0; rt < 4; rt++) {
            float a0 = acc[rt][kt][0], a1 = acc[rt][kt][1], a2v = acc[rt][kt][2], a3 = acc[rt][kt][3];
            float d0 = a0 - cc.z, d1 = a1 - cc.z, d2 = a2v - cc.z, d3 = a3 - cc.z;
            float v0 = cc.y*a0 + cc.x*d0*d0;
            float v1 = cc.y*a1 + cc.x*d1*d1;
            float v2 = cc.y*a2v + cc.x*d2*d2;
            float v3 = cc.y*a3 + cc.x*d3*d3;
            #pragma unroll
            for (int m = 1; m < 16; m <<= 1) {
                v0 += __shfl_xor(v0, m, 64);
                v1 += __shfl_xor(v1, m, 64);
                v2 += __shfl_xor(v2, m, 64);
                v3 += __shfl_xor(v3, m, 64);
            }
            float vv = (lm==0) ? v0 : (lm==1) ? v1 : (lm==2) ? v2 : v3;
            if (lm < 4) {
                int n = n0 + rg*64 + rt*16 + lg*4 + lm;
                out[(size_t)n*KC + kg0 + kk] = Ck + vv;
            }
        }
    }
}

// ================================ launch =====================================
extern "C" void kernel_launch(void* const* d_in, const int* in_sizes, int n_in,
                              void* d_out, int out_size, void* d_ws, size_t ws_size,
                              hipStream_t stream) {
    const float* x  = (const float*)d_in[0];
    const float* MU = (const float*)d_in[1];
    const float* A  = (const float*)d_in[2];
    const float* D  = (const float*)d_in[3];
    const float* PI = (const float*)d_in[4];
    float* out = (float*)d_out;
    char* ws   = (char*)d_ws;

    mfa_prep<<<KC, 256, 0, stream>>>(MU, A, D, PI, ws);
    mfa_main<<<dim3(4, N_PTS/128), 512, 0, stream>>>(x, ws, out);
}